// Round 12
// baseline (56.050 us; speedup 1.0000x reference)
//
#include <hip/hip_runtime.h>
#include <math.h>

#define QN 900
#define TN 100
#define CN 91
#define PN 1024
#define HWD 128
#define BS 2
#define QT 57          // ceil(900/16) q-tiles per batch
#define TPAD 112       // t rows padded to 7*16

typedef __bf16 bf16x8 __attribute__((ext_vector_type(8)));
typedef float f32x4 __attribute__((ext_vector_type(4)));

__device__ __forceinline__ float sigmoidf_(float x) {
    return 1.0f / (1.0f + __expf(-x));
}
__device__ __forceinline__ float softplusf_(float x) {
    return fmaxf(x, 0.0f) + __logf(1.0f + __expf(-fabsf(x)));
}
__device__ __forceinline__ unsigned short bfrne(float f) {   // RNE bf16
    unsigned u = __float_as_uint(f);
    return (unsigned short)((u + 0x7FFFu + ((u >> 16) & 1u)) >> 16);
}

// ---------------------------------------------------------------------------
// stage1: blocks [0,1800): sample one (b,q) mask at 1024 points (batched
// scattered loads -> deep MLP at natural occupancy), write bf16 pm/sg planes
// + exact f32 row sums. blocks [1800,2000): build B^T = tm as bf16 0/1
// [TPAD x 1024] per batch + popcount sums.
// ---------------------------------------------------------------------------
__global__ __launch_bounds__(256) void stage1_kernel(
    const float2* __restrict__ coords, const int* __restrict__ tmasks,
    const float* __restrict__ pmasks, unsigned short* __restrict__ plane_pm,
    unsigned short* __restrict__ plane_sg, unsigned short* __restrict__ tmbT,
    float* __restrict__ tmsum, float2* __restrict__ ssum)
{
    __shared__ float sred[8];
    __shared__ int cnt[4];
    const int bx = blockIdx.x;
    const int tid = threadIdx.x;
    const int wv = tid >> 6, lane = tid & 63;

    if (bx < BS * QN) {
        const int b = bx / QN;
        const float* mask = pmasks + (size_t)bx * (HWD * HWD);

        int a00[4], a01[4], a10[4], a11[4];
        float wxa[4], wya[4];
        unsigned fl[4];
#pragma unroll
        for (int c = 0; c < 4; ++c) {
            float2 cd = coords[b * PN + c * 256 + tid];
            float x = cd.x * (float)HWD - 0.5f;
            float y = cd.y * (float)HWD - 0.5f;
            float fx = floorf(x), fy = floorf(y);
            int x0 = (int)fx, y0 = (int)fy;
            int x1 = x0 + 1, y1 = y0 + 1;
            wxa[c] = x - fx; wya[c] = y - fy;
            int xc0 = min(max(x0, 0), HWD - 1), xc1 = min(max(x1, 0), HWD - 1);
            int yc0 = min(max(y0, 0), HWD - 1), yc1 = min(max(y1, 0), HWD - 1);
            a00[c] = yc0 * HWD + xc0; a01[c] = yc0 * HWD + xc1;
            a10[c] = yc1 * HWD + xc0; a11[c] = yc1 * HWD + xc1;
            fl[c] = (unsigned)((x0 >= 0) & (x0 < HWD))
                  | ((unsigned)((x1 >= 0) & (x1 < HWD)) << 1)
                  | ((unsigned)((y0 >= 0) & (y0 < HWD)) << 2)
                  | ((unsigned)((y1 >= 0) & (y1 < HWD)) << 3);
        }
        float r00[4], r01[4], r10[4], r11[4];
#pragma unroll
        for (int c = 0; c < 4; ++c) {
            r00[c] = mask[a00[c]];
            r01[c] = mask[a01[c]];
            r10[c] = mask[a10[c]];
            r11[c] = mask[a11[c]];
        }
        float lsp = 0.f, lsm = 0.f;
#pragma unroll
        for (int c = 0; c < 4; ++c) {
            bool bx0 = fl[c] & 1u, bx1 = fl[c] & 2u, by0 = fl[c] & 4u, by1 = fl[c] & 8u;
            float v00 = (by0 && bx0) ? r00[c] : 0.f;
            float v01 = (by0 && bx1) ? r01[c] : 0.f;
            float v10 = (by1 && bx0) ? r10[c] : 0.f;
            float v11 = (by1 && bx1) ? r11[c] : 0.f;
            float wx = wxa[c], wy = wya[c];
            float pm = (v00 * (1.f - wx) + v01 * wx) * (1.f - wy) +
                       (v10 * (1.f - wx) + v11 * wx) * wy;
            float sg = sigmoidf_(pm);
            lsp += softplusf_(pm);
            lsm += sg;
            const size_t po = (size_t)(b * (QT * 16) + (bx - b * QN)) * PN + c * 256 + tid;
            plane_pm[po] = bfrne(pm);
            plane_sg[po] = bfrne(sg);
        }
        for (int off = 32; off > 0; off >>= 1) {
            lsp += __shfl_down(lsp, off);
            lsm += __shfl_down(lsm, off);
        }
        if (lane == 0) { sred[wv * 2 + 0] = lsp; sred[wv * 2 + 1] = lsm; }
        __syncthreads();
        if (tid == 0)
            ssum[bx] = make_float2((sred[0] + sred[2]) + (sred[4] + sred[6]),
                                   (sred[1] + sred[3]) + (sred[5] + sred[7]));
    } else {
        const int bt = bx - BS * QN;          // [0,200)
        const int b = bt / TN, t = bt % TN;
        const int* m = tmasks + (size_t)(b * TN + t) * (HWD * HWD);
        int addr[4]; unsigned vld[4];
#pragma unroll
        for (int c = 0; c < 4; ++c) {
            float2 cd = coords[b * PN + c * 256 + tid];
            int xi = (int)rintf(cd.x * (float)HWD - 0.5f);
            int yi = (int)rintf(cd.y * (float)HWD - 0.5f);
            vld[c] = (xi >= 0) & (xi < HWD) & (yi >= 0) & (yi < HWD);
            addr[c] = min(max(yi, 0), HWD - 1) * HWD + min(max(xi, 0), HWD - 1);
        }
        int rv[4];
#pragma unroll
        for (int c = 0; c < 4; ++c) rv[c] = m[addr[c]];
        int mycnt = 0;
#pragma unroll
        for (int c = 0; c < 4; ++c) {
            const int bit = (vld[c] && (rv[c] != 0)) ? 1 : 0;
            tmbT[(size_t)(b * TPAD + t) * PN + c * 256 + tid] =
                bit ? (unsigned short)0x3F80 : (unsigned short)0;
            unsigned long long bal = __ballot(bit);
            if (lane == 0) mycnt += __popcll(bal);
        }
        if (lane == 0) cnt[wv] = mycnt;
        __syncthreads();
        if (tid == 0)
            tmsum[b * TN + t] = (float)((cnt[0] + cnt[1]) + (cnt[2] + cnt[3]));
    }
}

// ---------------------------------------------------------------------------
// gemm: 114 blocks (2 batches x 57 q-tiles) x 256 thr (4 waves). Wave w owns
// n-tiles {w, w+4}. MFMA f32_16x16x32_bf16 over K=1024 for pm & sg planes
// against B^T = tm. Fused cost epilogue from the D fragments.
// A-frag: row=lane&15, k=(lane>>4)*8+j. B-frag: col=lane&15, same k.
// D: col=lane&15, row=(lane>>4)*4+reg  [m89-verified].
// ---------------------------------------------------------------------------
__global__ __launch_bounds__(256) void gemm_kernel(
    const float* __restrict__ logits, const float4* __restrict__ pboxes,
    const int* __restrict__ labels, const float4* __restrict__ tboxes,
    const unsigned short* __restrict__ plane_pm,
    const unsigned short* __restrict__ plane_sg,
    const unsigned short* __restrict__ tmbT,
    const float* __restrict__ tmsum_, const float2* __restrict__ ssum,
    float* __restrict__ out, float* __restrict__ blockmax,
    int* __restrict__ badflag)
{
    __shared__ float wmax_s[4];
    __shared__ int wbad_s[4];

    const int bid = blockIdx.x;
    const int b = bid / QT, tile = bid - b * QT;
    const int q0 = tile * 16;
    const int tid = threadIdx.x;
    const int w = tid >> 6, lane = tid & 63;
    const int lr = lane & 15;
    const int lk = (lane >> 4) * 8;
    const int n0 = w;
    const int n1 = w + 4;
    const bool has1 = (n1 < 7);

    const size_t arow = (size_t)(b * (QT * 16) + q0 + lr) * PN + lk;
    const size_t brow0 = (size_t)(b * TPAD + n0 * 16 + lr) * PN + lk;
    const size_t brow1 = (size_t)(b * TPAD + (has1 ? n1 : n0) * 16 + lr) * PN + lk;

    f32x4 aP0 = {0.f, 0.f, 0.f, 0.f}, aS0 = {0.f, 0.f, 0.f, 0.f};
    f32x4 aP1 = {0.f, 0.f, 0.f, 0.f}, aS1 = {0.f, 0.f, 0.f, 0.f};
#pragma unroll 4
    for (int ks = 0; ks < 32; ++ks) {
        const int ko = ks * 32;
        bf16x8 af = *(const bf16x8*)(plane_pm + arow + ko);
        bf16x8 ag = *(const bf16x8*)(plane_sg + arow + ko);
        bf16x8 b0 = *(const bf16x8*)(tmbT + brow0 + ko);
        bf16x8 b1 = *(const bf16x8*)(tmbT + brow1 + ko);
        aP0 = __builtin_amdgcn_mfma_f32_16x16x32_bf16(af, b0, aP0, 0, 0, 0);
        aS0 = __builtin_amdgcn_mfma_f32_16x16x32_bf16(ag, b0, aS0, 0, 0, 0);
        aP1 = __builtin_amdgcn_mfma_f32_16x16x32_bf16(af, b1, aP1, 0, 0, 0);
        aS1 = __builtin_amdgcn_mfma_f32_16x16x32_bf16(ag, b1, aS1, 0, 0, 0);
    }

    float wmaxv = -INFINITY;
    int wbad = 0;
#pragma unroll
    for (int which = 0; which < 2; ++which) {
        if (which && !has1) break;
        const int n = which ? n1 : n0;
        const int t = n * 16 + lr;
        const bool tok = (t < TN);
        float tsum = 0.f; float4 tb = make_float4(0, 0, 0, 0); int lab = 0;
        if (tok) {
            tsum = tmsum_[b * TN + t];
            tb = tboxes[b * TN + t];
            lab = labels[b * TN + t];
        }
        const f32x4 ap = which ? aP1 : aP0;
        const f32x4 as = which ? aS1 : aS0;
#pragma unroll
        for (int r = 0; r < 4; ++r) {
            const int q = q0 + (lane >> 4) * 4 + r;
            if (!tok || q >= QN) continue;
            float2 ss = ssum[b * QN + q];
            float lg = logits[(size_t)(b * QN + q) * CN + lab];
            float4 pb = pboxes[b * QN + q];
            float apm = ap[r], asg = as[r];

            float ce = (ss.x - apm) * (1.0f / (float)PN);
            float dice = 1.0f - (2.0f * asg + 1.0f) / (ss.y + tsum + 1.0f);

            float pr = sigmoidf_(lg);
            float cls = 0.25f * (1.f - pr) * (1.f - pr) * softplusf_(-lg)
                      - 0.75f * pr * pr * softplusf_(lg);

            float l1 = fabsf(pb.x - tb.x) + fabsf(pb.y - tb.y) +
                       fabsf(pb.z - tb.z) + fabsf(pb.w - tb.w);

            float px1 = pb.x - 0.5f * pb.z, py1 = pb.y - 0.5f * pb.w;
            float px2 = pb.x + 0.5f * pb.z, py2 = pb.y + 0.5f * pb.w;
            float tx1 = tb.x - 0.5f * tb.z, ty1 = tb.y - 0.5f * tb.w;
            float tx2 = tb.x + 0.5f * tb.z, ty2 = tb.y + 0.5f * tb.w;
            float A1 = (px2 - px1) * (py2 - py1);
            float A2 = (tx2 - tx1) * (ty2 - ty1);
            float iw = fmaxf(fminf(px2, tx2) - fmaxf(px1, tx1), 0.f);
            float ih = fmaxf(fminf(py2, ty2) - fmaxf(py1, ty1), 0.f);
            float inter = iw * ih;
            float uni = A1 + A2 - inter;
            float iou = inter / uni;
            float cw = fmaxf(fmaxf(px2, tx2) - fminf(px1, tx1), 0.f);
            float chh = fmaxf(fmaxf(py2, ty2) - fminf(py1, ty1), 0.f);
            float area = cw * chh;
            float giou = iou - (area - uni) / area;

            float Cv = l1 + cls - giou + ce + dice;
            out[(size_t)(b * QN + q) * TN + t] = Cv;
            if (isfinite(Cv)) wmaxv = fmaxf(wmaxv, Cv);
            else wbad = 1;
        }
    }
    for (int off = 32; off > 0; off >>= 1)
        wmaxv = fmaxf(wmaxv, __shfl_down(wmaxv, off));
    wbad = (__ballot(wbad) != 0ull) ? 1 : 0;
    if (lane == 0) { wmax_s[w] = wmaxv; wbad_s[w] = wbad; }
    __syncthreads();
    if (tid == 0) {
        float m = fmaxf(fmaxf(wmax_s[0], wmax_s[1]), fmaxf(wmax_s[2], wmax_s[3]));
        blockmax[bid] = m;
        badflag[bid] = wbad_s[0] | wbad_s[1] | wbad_s[2] | wbad_s[3];
    }
}

// ---------------------------------------------------------------------------
// Fixup: C = where(finite, C, 2*max_finite) per batch; gated per q-tile.
// ---------------------------------------------------------------------------
__global__ __launch_bounds__(256) void fix_kernel(float* __restrict__ out,
                                                  const float* __restrict__ blockmax,
                                                  const int* __restrict__ badflag)
{
    const int bid = blockIdx.x;
    if (badflag[bid] == 0) return;      // uniform fast path
    const int b = bid / QT, tile = bid - b * QT;
    const int q0 = tile * 16;
    float m = -INFINITY;
    for (int k = 0; k < QT; ++k) m = fmaxf(m, blockmax[b * QT + k]);
    for (int idx = threadIdx.x; idx < 16 * TN; idx += 256) {
        const int q = q0 + idx / TN;
        if (q >= QN) break;
        const size_t o = (size_t)(b * QN + q) * TN + (idx % TN);
        float v = out[o];
        if (!isfinite(v)) out[o] = 2.0f * m;
    }
}

extern "C" void kernel_launch(void* const* d_in, const int* in_sizes, int n_in,
                              void* d_out, int out_size, void* d_ws, size_t ws_size,
                              hipStream_t stream) {
    const float* logits  = (const float*)d_in[0];
    const float4* pboxes = (const float4*)d_in[1];
    const int* labels    = (const int*)d_in[2];
    const float4* tboxes = (const float4*)d_in[3];
    const float* pmasks  = (const float*)d_in[4];
    const int* tmasks    = (const int*)d_in[5];
    const float* coords  = (const float*)d_in[6];
    float* out = (float*)d_out;

    char* ws = (char*)d_ws;
    unsigned short* plane_pm = (unsigned short*)(ws);             // 2*912*1024*2 = 3,735,552
    unsigned short* plane_sg = (unsigned short*)(ws + 3735552);   // 3,735,552
    unsigned short* tmbT     = (unsigned short*)(ws + 7471104);   // 2*112*1024*2 = 458,752
    float* tmsum    = (float*)(ws + 7929856);                     // 800
    float2* ssum    = (float2*)(ws + 7930656);                    // 14,400
    float* blockmax = (float*)(ws + 7945056);                     // 456
    int* badflag    = (int*)(ws + 7945520);                       // 456

    hipLaunchKernelGGL(stage1_kernel, dim3(BS * QN + BS * TN), dim3(256), 0, stream,
                       (const float2*)coords, tmasks, pmasks, plane_pm, plane_sg,
                       tmbT, tmsum, ssum);
    hipLaunchKernelGGL(gemm_kernel, dim3(BS * QT), dim3(256), 0, stream,
                       logits, pboxes, labels, tboxes, plane_pm, plane_sg, tmbT,
                       tmsum, ssum, out, blockmax, badflag);
    hipLaunchKernelGGL(fix_kernel, dim3(BS * QT), dim3(256), 0, stream,
                       out, blockmax, badflag);
}